// Round 1
// baseline (61.063 us; speedup 1.0000x reference)
//
#include <hip/hip_runtime.h>

#define SEQ 65536
#define HID 1024

// ---- ordered-uint transform for float atomicMax ----
// monotonic: f1 < f2  <=>  f2ord(f1) < f2ord(f2) (unsigned).
// f2ord^{-1}(0) is below every encodable float, so memset-0 init == -inf.
__device__ __forceinline__ unsigned f2ord(float f) {
    unsigned b = __float_as_uint(f);
    return (b & 0x80000000u) ? ~b : (b | 0x80000000u);
}
__device__ __forceinline__ float ord2f(unsigned u) {
    return (u & 0x80000000u) ? __uint_as_float(u ^ 0x80000000u)
                             : __uint_as_float(~u);
}

// K1: energies[r] = enc[r,:] . hid  (one wave per row), fused global max.
__global__ __launch_bounds__(256) void k_matvec_max(
        const float* __restrict__ enc,
        const float* __restrict__ hid,
        float* __restrict__ energies,      // d_out reused as scratch
        unsigned* __restrict__ maxacc) {
    const int lane = threadIdx.x & 63;
    const int wid  = threadIdx.x >> 6;            // wave within block (0..3)
    const int gw   = blockIdx.x * 4 + wid;        // global wave id
    const int nw   = gridDim.x * 4;

    // hoist hidden into 16 regs/lane (row-invariant)
    const float4* __restrict__ h4 = (const float4*)hid;
    const float4 h0 = h4[lane];
    const float4 h1 = h4[lane + 64];
    const float4 h2 = h4[lane + 128];
    const float4 h3 = h4[lane + 192];

    float wmax = -INFINITY;
    for (int r = gw; r < SEQ; r += nw) {
        const float4* __restrict__ row = (const float4*)(enc + (size_t)r * HID);
        float4 a0 = row[lane];
        float4 a1 = row[lane + 64];
        float4 a2 = row[lane + 128];
        float4 a3 = row[lane + 192];
        float s = a0.x*h0.x + a0.y*h0.y + a0.z*h0.z + a0.w*h0.w
                + a1.x*h1.x + a1.y*h1.y + a1.z*h1.z + a1.w*h1.w
                + a2.x*h2.x + a2.y*h2.y + a2.z*h2.z + a2.w*h2.w
                + a3.x*h3.x + a3.y*h3.y + a3.z*h3.z + a3.w*h3.w;
        #pragma unroll
        for (int off = 32; off >= 1; off >>= 1)
            s += __shfl_xor(s, off, 64);
        if (lane == 0) energies[r] = s;
        wmax = fmaxf(wmax, s);                    // same value in all lanes
    }

    __shared__ float smax[4];
    if (lane == 0) smax[wid] = wmax;
    __syncthreads();
    if (threadIdx.x == 0) {
        float m = fmaxf(fmaxf(smax[0], smax[1]), fmaxf(smax[2], smax[3]));
        atomicMax(maxacc, f2ord(m));
    }
}

// K2: in-place p = exp(e - max); block-partial sums -> atomicAdd.
__global__ __launch_bounds__(256) void k_exp_sum(
        float* __restrict__ out,
        const unsigned* __restrict__ maxacc,
        float* __restrict__ sumacc) {
    const float m = ord2f(*maxacc);
    const int i = blockIdx.x * 256 + threadIdx.x;
    float p = __expf(out[i] - m);
    out[i] = p;

    float s = p;
    #pragma unroll
    for (int off = 32; off >= 1; off >>= 1)
        s += __shfl_xor(s, off, 64);

    __shared__ float ssum[4];
    if ((threadIdx.x & 63) == 0) ssum[threadIdx.x >> 6] = s;
    __syncthreads();
    if (threadIdx.x == 0)
        atomicAdd(sumacc, ssum[0] + ssum[1] + ssum[2] + ssum[3]);
}

// K3: normalize.
__global__ __launch_bounds__(256) void k_scale(
        float* __restrict__ out,
        const float* __restrict__ sumacc) {
    const float inv = 1.0f / *sumacc;
    const int i = blockIdx.x * 256 + threadIdx.x;
    out[i] *= inv;
}

extern "C" void kernel_launch(void* const* d_in, const int* in_sizes, int n_in,
                              void* d_out, int out_size, void* d_ws, size_t ws_size,
                              hipStream_t stream) {
    const float* hid = (const float*)d_in[0];   // hidden   [1024]
    const float* enc = (const float*)d_in[1];   // encoder  [65536,1024]
    float* out = (float*)d_out;                 // [65536]

    unsigned* maxacc = (unsigned*)d_ws;         // ordered-uint max
    float*    sumacc = (float*)d_ws + 1;        // exp-sum

    // init both accumulators (0 == -inf in ordered encoding; 0.0f for sum)
    hipMemsetAsync(d_ws, 0, 8, stream);

    k_matvec_max<<<2048, 256, 0, stream>>>(enc, hid, out, maxacc);
    k_exp_sum  <<<SEQ / 256, 256, 0, stream>>>(out, maxacc, sumacc);
    k_scale    <<<SEQ / 256, 256, 0, stream>>>(out, sumacc);
}

// Round 3
// 48.112 us; speedup vs baseline: 1.2692x; 1.2692x over previous
//
#include <hip/hip_runtime.h>

#define SEQ 65536
#define HID 1024
#define K1_BLOCKS 2048
#define WPB 4                       // waves per block
#define NWAVES (K1_BLOCKS * WPB)    // 8192
#define RPW (SEQ / NWAVES)          // 8 rows per wave, contiguous chunk

typedef float f4 __attribute__((ext_vector_type(4)));   // native vec, OK for nontemporal builtin

// K1: energies[r] = enc[r,:] . hid (one wave per row), plus per-block
// online-softmax stats (max, sum_exp) written to ws slots (no atomics).
__global__ __launch_bounds__(256) void k_matvec_stats(
        const float* __restrict__ enc,
        const float* __restrict__ hid,
        float* __restrict__ energies,      // d_out reused as scratch
        float2* __restrict__ stats) {      // ws[0..2047]
    const int lane = threadIdx.x & 63;
    const int wid  = threadIdx.x >> 6;
    const int gw   = blockIdx.x * WPB + wid;
    const size_t base = (size_t)gw * RPW;

    // hidden hoisted into 16 regs/lane (row-invariant, L2-resident)
    const f4* __restrict__ h4 = (const f4*)hid;
    const f4 h0 = h4[lane];
    const f4 h1 = h4[lane + 64];
    const f4 h2 = h4[lane + 128];
    const f4 h3 = h4[lane + 192];

    float wmax = -INFINITY, wsum = 0.0f;
    #pragma unroll
    for (int r = 0; r < RPW; ++r) {
        const f4* __restrict__ row = (const f4*)(enc + (base + r) * HID);
        f4 a0 = __builtin_nontemporal_load(row + lane);
        f4 a1 = __builtin_nontemporal_load(row + lane + 64);
        f4 a2 = __builtin_nontemporal_load(row + lane + 128);
        f4 a3 = __builtin_nontemporal_load(row + lane + 192);
        float s = a0.x*h0.x + a0.y*h0.y + a0.z*h0.z + a0.w*h0.w
                + a1.x*h1.x + a1.y*h1.y + a1.z*h1.z + a1.w*h1.w
                + a2.x*h2.x + a2.y*h2.y + a2.z*h2.z + a2.w*h2.w
                + a3.x*h3.x + a3.y*h3.y + a3.z*h3.z + a3.w*h3.w;
        #pragma unroll
        for (int off = 32; off >= 1; off >>= 1)
            s += __shfl_xor(s, off, 64);
        if (lane == 0) energies[base + r] = s;
        // online max/sum (all lanes hold identical s)
        float nm = fmaxf(wmax, s);
        wsum = wsum * __expf(wmax - nm) + __expf(s - nm);
        wmax = nm;
    }

    __shared__ float sm[WPB], ss[WPB];
    if (lane == 0) { sm[wid] = wmax; ss[wid] = wsum; }
    __syncthreads();
    if (threadIdx.x == 0) {
        float m = fmaxf(fmaxf(sm[0], sm[1]), fmaxf(sm[2], sm[3]));
        float s = ss[0]*__expf(sm[0]-m) + ss[1]*__expf(sm[1]-m)
                + ss[2]*__expf(sm[2]-m) + ss[3]*__expf(sm[3]-m);
        stats[blockIdx.x] = make_float2(m, s);
    }
}

// K2: every block redundantly reduces the 2048 (max,sum) stats (16 KiB,
// L2-hit), then exp+normalizes its 1024-element chunk in one pass.
__global__ __launch_bounds__(256) void k_softmax_scale(
        float* __restrict__ out,
        const float2* __restrict__ stats) {
    float m = -INFINITY, s = 0.0f;
    #pragma unroll
    for (int k = 0; k < K1_BLOCKS / 256; ++k) {
        float2 st = stats[k * 256 + threadIdx.x];
        float nm = fmaxf(m, st.x);
        s = s * __expf(m - nm) + st.y * __expf(st.x - nm);
        m = nm;
    }
    #pragma unroll
    for (int off = 32; off >= 1; off >>= 1) {
        float om = __shfl_xor(m, off, 64);
        float os = __shfl_xor(s, off, 64);
        float nm = fmaxf(m, om);
        s = s * __expf(m - nm) + os * __expf(om - nm);
        m = nm;
    }
    __shared__ float sm[4], ss[4];
    const int lane = threadIdx.x & 63, wid = threadIdx.x >> 6;
    if (lane == 0) { sm[wid] = m; ss[wid] = s; }
    __syncthreads();
    const float M = fmaxf(fmaxf(sm[0], sm[1]), fmaxf(sm[2], sm[3]));
    const float S = ss[0]*__expf(sm[0]-M) + ss[1]*__expf(sm[1]-M)
                  + ss[2]*__expf(sm[2]-M) + ss[3]*__expf(sm[3]-M);
    const float invS = 1.0f / S;

    const int i = (blockIdx.x * 256 + threadIdx.x) * 4;
    float4 e = *(const float4*)(out + i);
    e.x = __expf(e.x - M) * invS;
    e.y = __expf(e.y - M) * invS;
    e.z = __expf(e.z - M) * invS;
    e.w = __expf(e.w - M) * invS;
    *(float4*)(out + i) = e;
}

extern "C" void kernel_launch(void* const* d_in, const int* in_sizes, int n_in,
                              void* d_out, int out_size, void* d_ws, size_t ws_size,
                              hipStream_t stream) {
    const float* hid = (const float*)d_in[0];   // hidden   [1024]
    const float* enc = (const float*)d_in[1];   // encoder  [65536,1024]
    float* out = (float*)d_out;                 // [65536]
    float2* stats = (float2*)d_ws;              // 2048 * 8 B = 16 KiB

    k_matvec_stats  <<<K1_BLOCKS, 256, 0, stream>>>(enc, hid, out, stats);
    k_softmax_scale <<<SEQ / (256 * 4), 256, 0, stream>>>(out, stats);
}